// Round 1
// baseline (138.272 us; speedup 1.0000x reference)
//
#include <hip/hip_runtime.h>
#include <hip/hip_bf16.h>

#define T_DIM 6
#define N_NODES 10000
#define TOTAL_ROWS (T_DIM * N_NODES)   // 60000
#define SCALE 0.25f                    // dh^-0.5, dh=16
#define EPS_GATE 1e-6f

typedef unsigned short u16;

__device__ __forceinline__ float red16(float x) {
    x += __shfl_xor(x, 1);
    x += __shfl_xor(x, 2);
    x += __shfl_xor(x, 4);
    x += __shfl_xor(x, 8);
    return x;  // sum over each 16-lane group (one head)
}

__device__ __forceinline__ float bf2f(u16 u) {
    union { unsigned int i; float f; } c;
    c.i = ((unsigned int)u) << 16;
    return c.f;
}

__device__ __forceinline__ u16 f2bf(float f) {
    union { float f; unsigned int i; } c; c.f = f;
    unsigned int i = c.i;
    unsigned int lsb = (i >> 16) & 1u;
    i += 0x7FFFu + lsb;          // round-to-nearest-even (finite data only)
    return (u16)(i >> 16);
}

// ---------------- prep: gate table, K_pe table, degree counts ----------------
__global__ void prep_kernel(const float* __restrict__ S,
                            const float* __restrict__ Wk,     // (64,72)
                            const int* __restrict__ edge_dst, // E
                            float* __restrict__ gate,         // [N][T]
                            float* __restrict__ kpe,          // [9][64]
                            float* __restrict__ bias,         // [9]
                            int* __restrict__ counts, int E) {
    int idx = blockIdx.x * blockDim.x + threadIdx.x;
    if (idx < TOTAL_ROWS) {
        int t = idx / N_NODES, n = idx - t * N_NODES;
        gate[n * T_DIM + t] = logf(S[idx] + EPS_GATE);
    }
    if (idx < E) atomicAdd(&counts[edge_dst[idx]], 1);
    if (blockIdx.x == 0 && threadIdx.x < 64) {
        int c = threadIdx.x;
        for (int dt = 0; dt < 9; ++dt) {
            float fdt = (float)dt;
            float pe[8];
            pe[0] = expf(-fdt * 0.25f);    // tau=4
            pe[1] = expf(-fdt * 0.0625f);  // tau=16
            pe[2] = sinf(fdt * 1.0f);
            pe[3] = sinf(fdt * 0.5f);
            pe[4] = sinf(fdt * 0.25f);
            pe[5] = cosf(fdt * 1.0f);
            pe[6] = cosf(fdt * 0.5f);
            pe[7] = cosf(fdt * 0.25f);
            float acc = 0.f;
            #pragma unroll
            for (int j = 0; j < 8; ++j) acc += pe[j] * Wk[c * 72 + 64 + j];
            kpe[dt * 64 + c] = acc;
            if (c == 0) bias[dt] = -logf(1.0f + fdt);
        }
    }
}

// ---------------- single-block exclusive scan -> CSR row_ptr ----------------
#define SCAN_THREADS 1024
#define SCAN_CHUNK 10            // 1024*10 >= 10000
__global__ void scan_kernel(const int* __restrict__ counts,
                            int* __restrict__ row_ptr,   // N+1
                            int* __restrict__ cursor) {
    __shared__ int sums[SCAN_THREADS];
    int tid = threadIdx.x;
    int start = tid * SCAN_CHUNK;
    int local[SCAN_CHUNK];
    int s = 0;
    #pragma unroll
    for (int j = 0; j < SCAN_CHUNK; ++j) {
        int idx = start + j;
        int v = (idx < N_NODES) ? counts[idx] : 0;
        local[j] = s; s += v;
    }
    sums[tid] = s;
    __syncthreads();
    for (int off = 1; off < SCAN_THREADS; off <<= 1) {
        int v = sums[tid];
        int o = (tid >= off) ? sums[tid - off] : 0;
        __syncthreads();
        sums[tid] = v + o;
        __syncthreads();
    }
    int base = (tid > 0) ? sums[tid - 1] : 0;
    #pragma unroll
    for (int j = 0; j < SCAN_CHUNK; ++j) {
        int idx = start + j;
        if (idx < N_NODES) {
            int val = base + local[j];
            row_ptr[idx] = val;
            cursor[idx] = val;
        }
    }
    if (tid == SCAN_THREADS - 1) row_ptr[N_NODES] = sums[SCAN_THREADS - 1];
}

// ---------------- scatter edges into CSR buckets ----------------
__global__ void scatter_kernel(const int* __restrict__ esrc, const int* __restrict__ edst,
                               int* __restrict__ cursor, int* __restrict__ edge_src, int E) {
    int e = blockIdx.x * blockDim.x + threadIdx.x;
    if (e < E) {
        int pos = atomicAdd(&cursor[edst[e]], 1);
        edge_src[pos] = esrc[e];
    }
}

// ---------------- fused QKV projection ----------------
// Q (prescaled by SCALE) -> d_out laid out [t][n][64] (f32)
// K_H, V -> bf16, transposed [n][t][64]
__global__ __launch_bounds__(256) void proj_kernel(
    const float* __restrict__ H,
    const float* __restrict__ Wq, const float* __restrict__ Wk,
    const float* __restrict__ Wv,
    float* __restrict__ Qs, u16* __restrict__ Kb, u16* __restrict__ Vb) {
    __shared__ float wqT[64][66], wkT[64][66], wvT[64][66];
    int tid = threadIdx.x;
    for (int i = tid; i < 4096; i += 256) {
        int c = i >> 6, k = i & 63;
        wqT[k][c] = Wq[c * 64 + k];
        wkT[k][c] = Wk[c * 72 + k];   // first 64 input dims of W_k
        wvT[k][c] = Wv[c * 64 + k];
    }
    __syncthreads();
    int lane = tid & 63, w = tid >> 6;
    int r0 = (blockIdx.x * 4 + w) * 8;               // 8 rows per wave, 60000 % 32 == 0
    const float* __restrict__ hrow = H + (size_t)r0 * 64;
    float aq[8] = {0,0,0,0,0,0,0,0};
    float ak[8] = {0,0,0,0,0,0,0,0};
    float av[8] = {0,0,0,0,0,0,0,0};
    #pragma unroll 8
    for (int k = 0; k < 64; ++k) {
        float wq = wqT[k][lane];
        float wkk = wkT[k][lane];
        float wv = wvT[k][lane];
        #pragma unroll
        for (int j = 0; j < 8; ++j) {
            float h = hrow[j * 64 + k];              // wave-uniform broadcast load
            aq[j] = fmaf(h, wq, aq[j]);
            ak[j] = fmaf(h, wkk, ak[j]);
            av[j] = fmaf(h, wv, av[j]);
        }
    }
    #pragma unroll
    for (int j = 0; j < 8; ++j) {
        int row = r0 + j;
        Qs[(size_t)row * 64 + lane] = aq[j] * SCALE;
        int t = row / N_NODES, n = row - t * N_NODES;
        size_t o = ((size_t)n * T_DIM + t) * 64 + lane;
        Kb[o] = f2bf(ak[j]);
        Vb[o] = f2bf(av[j]);
    }
}

// ---------------- aggregation: one wave per node ----------------
__global__ __launch_bounds__(256) void agg_kernel(
    const float* __restrict__ Qs,     // [t][n][64], prescaled (aliases out)
    const u16* __restrict__ Kb,       // [n][t][64] bf16
    const u16* __restrict__ Vb,
    const float* __restrict__ gate,   // [n][t]
    const float* __restrict__ kpe,    // [9][64]
    const float* __restrict__ bias,   // [9]
    const int* __restrict__ row_ptr,
    const int* __restrict__ edge_src,
    float* __restrict__ out) {
    int lane = threadIdx.x & 63, w = threadIdx.x >> 6;
    int n = blockIdx.x * 4 + w;
    if (n >= N_NODES) return;

    float q[T_DIM];
    #pragma unroll
    for (int t = 0; t < T_DIM; ++t) q[t] = Qs[((size_t)t * N_NODES + n) * 64 + lane];

    // cc[tri(t,dt)] = dot16(q_scaled[t], K_pe[dt]) + rel_bias[dt]  (uniform per head group)
    float cc[21];
    {
        float kp[T_DIM];
        #pragma unroll
        for (int dt = 0; dt < T_DIM; ++dt) kp[dt] = kpe[dt * 64 + lane];
        #pragma unroll
        for (int t = 0; t < T_DIM; ++t) {
            #pragma unroll
            for (int dt = 0; dt <= t; ++dt) {
                cc[t * (t + 1) / 2 + dt] = red16(q[t] * kp[dt]) + bias[dt];
            }
        }
    }

    float numer[T_DIM] = {0,0,0,0,0,0};
    float denom[T_DIM] = {0,0,0,0,0,0};
    int e0 = row_ptr[n], e1 = row_ptr[n + 1];
    for (int e = e0; e < e1; ++e) {
        int s = edge_src[e];                         // wave-uniform
        const u16* kb = Kb + (size_t)s * (T_DIM * 64) + lane;
        const u16* vb = Vb + (size_t)s * (T_DIM * 64) + lane;
        float kv[T_DIM], vv[T_DIM], g[T_DIM];
        #pragma unroll
        for (int tp = 0; tp < T_DIM; ++tp) {
            kv[tp] = bf2f(kb[tp * 64]);
            vv[tp] = bf2f(vb[tp * 64]);
            g[tp] = gate[s * T_DIM + tp];
        }
        #pragma unroll
        for (int t = 0; t < T_DIM; ++t) {
            #pragma unroll
            for (int dt = 0; dt <= t; ++dt) {
                int tp = t - dt;
                float sc = red16(q[t] * kv[tp]) + cc[t * (t + 1) / 2 + dt] + g[tp];
                float wt = __expf(sc);               // no max-shift: scores bounded, ratio exact
                denom[t] += wt;
                numer[t] = fmaf(wt, vv[tp], numer[t]);
            }
        }
    }
    #pragma unroll
    for (int t = 0; t < T_DIM; ++t) {
        out[((size_t)t * N_NODES + n) * 64 + lane] = numer[t] / fmaxf(denom[t], 1e-12f);
    }
}

extern "C" void kernel_launch(void* const* d_in, const int* in_sizes, int n_in,
                              void* d_out, int out_size, void* d_ws, size_t ws_size,
                              hipStream_t stream) {
    const float* H  = (const float*)d_in[0];
    const float* S  = (const float*)d_in[1];
    const float* Wq = (const float*)d_in[2];
    const float* Wk = (const float*)d_in[3];
    const float* Wv = (const float*)d_in[4];
    const int* edge = (const int*)d_in[5];
    int E = in_sizes[5] / 2;
    const int* esrc = edge;
    const int* edst = edge + E;
    float* out = (float*)d_out;

    char* ws = (char*)d_ws;
    size_t off = 0;
    auto alloc = [&](size_t b) { char* p = ws + off; off += (b + 255) & ~(size_t)255; return (void*)p; };
    u16*   Kb       = (u16*)  alloc((size_t)TOTAL_ROWS * 64 * 2);   // 7.68 MB
    u16*   Vb       = (u16*)  alloc((size_t)TOTAL_ROWS * 64 * 2);   // 7.68 MB
    float* gate     = (float*)alloc((size_t)TOTAL_ROWS * 4);        // 240 KB
    float* kpe      = (float*)alloc(9 * 64 * 4);
    float* bias     = (float*)alloc(9 * 4);
    int*   counts   = (int*)  alloc((size_t)N_NODES * 4);
    int*   cursor   = (int*)  alloc((size_t)N_NODES * 4);
    int*   row_ptr  = (int*)  alloc((size_t)(N_NODES + 1) * 4);
    int*   edge_src = (int*)  alloc((size_t)E * 4);

    hipMemsetAsync(counts, 0, (size_t)N_NODES * sizeof(int), stream);
    prep_kernel<<<(TOTAL_ROWS + 255) / 256, 256, 0, stream>>>(S, Wk, edst, gate, kpe, bias, counts, E);
    scan_kernel<<<1, SCAN_THREADS, 0, stream>>>(counts, row_ptr, cursor);
    scatter_kernel<<<(E + 255) / 256, 256, 0, stream>>>(esrc, edst, cursor, edge_src, E);
    proj_kernel<<<TOTAL_ROWS / 32, 256, 0, stream>>>(H, Wq, Wk, Wv, out, Kb, Vb);
    agg_kernel<<<(N_NODES + 3) / 4, 256, 0, stream>>>(out, Kb, Vb, gate, kpe, bias, row_ptr, edge_src, out);
}

// Round 2
// 97.938 us; speedup vs baseline: 1.4118x; 1.4118x over previous
//
#include <hip/hip_runtime.h>
#include <hip/hip_bf16.h>

#define T_DIM 6
#define N_NODES 10000
#define TOTAL_ROWS (T_DIM * N_NODES)   // 60000
#define LOG2E 1.44269504088896340736f
#define QPRE (0.25f * LOG2E)           // dh^-0.5 * log2(e): softmax done in exp2 domain
#define EPS_GATE 1e-6f
#define NEGBIG (-1e30f)

typedef unsigned int u32;
typedef unsigned short u16;

__device__ __forceinline__ float fast_exp2(float x) {
#if __has_builtin(__builtin_amdgcn_exp2f)
    return __builtin_amdgcn_exp2f(x);
#else
    return exp2f(x);
#endif
}

// DPP butterfly add within 8-lane groups: xor1 (quad_perm), xor2 (quad_perm),
// xor{4-ish} via row_half_mirror (l -> 7-l within each 8-lane half-row).
template <int CTRL>
__device__ __forceinline__ float dpp_add(float x) {
    int v = __builtin_amdgcn_update_dpp(0, __float_as_int(x), CTRL, 0xf, 0xf, true);
    return x + __int_as_float(v);
}
__device__ __forceinline__ float red8(float x) {
    x = dpp_add<0xB1>(x);   // quad_perm {1,0,3,2}  : lane ^ 1
    x = dpp_add<0x4E>(x);   // quad_perm {2,3,0,1}  : lane ^ 2
    x = dpp_add<0x141>(x);  // row_half_mirror      : l -> 7-l within 8 (adds other quad's sum)
    return x;               // all 8 lanes of the group hold the full sum
}

__device__ __forceinline__ u16 f2bf(float f) {
    union { float f; unsigned int i; } c; c.f = f;
    unsigned int i = c.i;
    unsigned int lsb = (i >> 16) & 1u;
    i += 0x7FFFu + lsb;          // round-to-nearest-even (finite data only)
    return (u16)(i >> 16);
}

// ---------------- prep: gate table (log2 domain), K_pe table, degree counts ----------------
__global__ void prep_kernel(const float* __restrict__ S,
                            const float* __restrict__ Wk,     // (64,72)
                            const int* __restrict__ edge_dst, // E
                            float* __restrict__ gate,         // [N][T], log2(S+eps)
                            float* __restrict__ kpe,          // [9][64]
                            float* __restrict__ bias,         // [9], -log2(1+dt)
                            int* __restrict__ counts, int E) {
    int idx = blockIdx.x * blockDim.x + threadIdx.x;
    if (idx < TOTAL_ROWS) {
        int t = idx / N_NODES, n = idx - t * N_NODES;
        gate[n * T_DIM + t] = log2f(S[idx] + EPS_GATE);
    }
    if (idx < E) atomicAdd(&counts[edge_dst[idx]], 1);
    if (blockIdx.x == 0 && threadIdx.x < 64) {
        int c = threadIdx.x;
        for (int dt = 0; dt < 9; ++dt) {
            float fdt = (float)dt;
            float pe[8];
            pe[0] = expf(-fdt * 0.25f);    // tau=4
            pe[1] = expf(-fdt * 0.0625f);  // tau=16
            pe[2] = sinf(fdt * 1.0f);
            pe[3] = sinf(fdt * 0.5f);
            pe[4] = sinf(fdt * 0.25f);
            pe[5] = cosf(fdt * 1.0f);
            pe[6] = cosf(fdt * 0.5f);
            pe[7] = cosf(fdt * 0.25f);
            float acc = 0.f;
            #pragma unroll
            for (int j = 0; j < 8; ++j) acc += pe[j] * Wk[c * 72 + 64 + j];
            kpe[dt * 64 + c] = acc;
            if (c == 0) bias[dt] = -log2f(1.0f + fdt);
        }
    }
}

// ---------------- single-block exclusive scan -> CSR row_ptr ----------------
#define SCAN_THREADS 1024
#define SCAN_CHUNK 10            // 1024*10 >= 10000
__global__ void scan_kernel(const int* __restrict__ counts,
                            int* __restrict__ row_ptr,   // N+1
                            int* __restrict__ cursor) {
    __shared__ int sums[SCAN_THREADS];
    int tid = threadIdx.x;
    int start = tid * SCAN_CHUNK;
    int local[SCAN_CHUNK];
    int s = 0;
    #pragma unroll
    for (int j = 0; j < SCAN_CHUNK; ++j) {
        int idx = start + j;
        int v = (idx < N_NODES) ? counts[idx] : 0;
        local[j] = s; s += v;
    }
    sums[tid] = s;
    __syncthreads();
    for (int off = 1; off < SCAN_THREADS; off <<= 1) {
        int v = sums[tid];
        int o = (tid >= off) ? sums[tid - off] : 0;
        __syncthreads();
        sums[tid] = v + o;
        __syncthreads();
    }
    int base = (tid > 0) ? sums[tid - 1] : 0;
    #pragma unroll
    for (int j = 0; j < SCAN_CHUNK; ++j) {
        int idx = start + j;
        if (idx < N_NODES) {
            int val = base + local[j];
            row_ptr[idx] = val;
            cursor[idx] = val;
        }
    }
    if (tid == SCAN_THREADS - 1) row_ptr[N_NODES] = sums[SCAN_THREADS - 1];
}

// ---------------- scatter edges into CSR buckets ----------------
__global__ void scatter_kernel(const int* __restrict__ esrc, const int* __restrict__ edst,
                               int* __restrict__ cursor, int* __restrict__ edge_src, int E) {
    int e = blockIdx.x * blockDim.x + threadIdx.x;
    if (e < E) {
        int pos = atomicAdd(&cursor[edst[e]], 1);
        edge_src[pos] = esrc[e];
    }
}

// ---------------- fused QKV projection ----------------
// Q (prescaled by QPRE) -> d_out laid out [t][n][64] (f32)
// K_H, V -> bf16, transposed [n][t][64]
__global__ __launch_bounds__(256) void proj_kernel(
    const float* __restrict__ H,
    const float* __restrict__ Wq, const float* __restrict__ Wk,
    const float* __restrict__ Wv,
    float* __restrict__ Qs, u16* __restrict__ Kb, u16* __restrict__ Vb) {
    __shared__ float wqT[64][66], wkT[64][66], wvT[64][66];
    int tid = threadIdx.x;
    for (int i = tid; i < 4096; i += 256) {
        int c = i >> 6, k = i & 63;
        wqT[k][c] = Wq[c * 64 + k];
        wkT[k][c] = Wk[c * 72 + k];   // first 64 input dims of W_k
        wvT[k][c] = Wv[c * 64 + k];
    }
    __syncthreads();
    int lane = tid & 63, w = tid >> 6;
    int r0 = (blockIdx.x * 4 + w) * 8;               // 8 rows per wave, 60000 % 32 == 0
    const float* __restrict__ hrow = H + (size_t)r0 * 64;
    float aq[8] = {0,0,0,0,0,0,0,0};
    float ak[8] = {0,0,0,0,0,0,0,0};
    float av[8] = {0,0,0,0,0,0,0,0};
    #pragma unroll 8
    for (int k = 0; k < 64; ++k) {
        float wq = wqT[k][lane];
        float wkk = wkT[k][lane];
        float wv = wvT[k][lane];
        #pragma unroll
        for (int j = 0; j < 8; ++j) {
            float h = hrow[j * 64 + k];              // wave-uniform broadcast load
            aq[j] = fmaf(h, wq, aq[j]);
            ak[j] = fmaf(h, wkk, ak[j]);
            av[j] = fmaf(h, wv, av[j]);
        }
    }
    #pragma unroll
    for (int j = 0; j < 8; ++j) {
        int row = r0 + j;
        Qs[(size_t)row * 64 + lane] = aq[j] * QPRE;
        int t = row / N_NODES, n = row - t * N_NODES;
        size_t o = ((size_t)n * T_DIM + t) * 64 + lane;
        Kb[o] = f2bf(ak[j]);
        Vb[o] = f2bf(av[j]);
    }
}

// ---------------- aggregation: one wave per node, 2 edges per iteration ----------------
// lanes: [half(2 edges)][head(4)][pair(8)], each lane owns 2 consecutive dims.
__global__ __launch_bounds__(256) void agg_kernel(
    const float* __restrict__ Qs,     // [t][n][64], prescaled by QPRE (aliases out)
    const u16* __restrict__ Kb,       // [n][t][64] bf16
    const u16* __restrict__ Vb,
    const float* __restrict__ gate,   // [n][t]  log2(S+eps)
    const float* __restrict__ kpe,    // [9][64]
    const float* __restrict__ bias,   // [9]  -log2(1+dt)
    const int* __restrict__ row_ptr,
    const int* __restrict__ edge_src,
    float* __restrict__ out) {
    int lane = threadIdx.x & 63, w = threadIdx.x >> 6;
    int n = blockIdx.x * 4 + w;
    int half = lane >> 5;
    int l32 = lane & 31;
    int doff = ((l32 >> 3) << 4) + ((l32 & 7) << 1);   // h*16 + 2*p

    float q0[T_DIM], q1[T_DIM];
    #pragma unroll
    for (int t = 0; t < T_DIM; ++t) {
        float2 qq = *(const float2*)(Qs + ((size_t)t * N_NODES + n) * 64 + doff);
        q0[t] = qq.x; q1[t] = qq.y;
    }

    int e0 = row_ptr[n], e1 = row_ptr[n + 1];
    if (e0 >= e1) {                                    // zero-degree: output 0 (matches ref clip)
        if (half == 0) {
            #pragma unroll
            for (int t = 0; t < T_DIM; ++t)
                *(float2*)(out + ((size_t)t * N_NODES + n) * 64 + doff) = make_float2(0.f, 0.f);
        }
        return;
    }

    // cc[tri(t,dt)] = dot(q[t], K_pe[dt]) + bias[dt]   (log2 domain; uniform per head group)
    float cc[21];
    #pragma unroll
    for (int dt = 0; dt < T_DIM; ++dt) {
        float2 kp = *(const float2*)(kpe + dt * 64 + doff);
        float b = bias[dt];
        #pragma unroll
        for (int t = dt; t < T_DIM; ++t)
            cc[t * (t + 1) / 2 + dt] = red8(fmaf(q1[t], kp.y, q0[t] * kp.x)) + b;
    }

    float den[T_DIM] = {0,0,0,0,0,0};
    float nu0[T_DIM] = {0,0,0,0,0,0};
    float nu1[T_DIM] = {0,0,0,0,0,0};

    int npairs = (e1 - e0 + 1) >> 1;
    u32 ku[T_DIM], vu[T_DIM];
    float gg[T_DIM];

    // prologue: load pair 0 (this half's edge; odd tail padded via g = -1e30 -> weight 0)
    {
        int i = e0 + half;
        int s = edge_src[min(i, e1 - 1)];
        const u16* kb = Kb + (size_t)s * (T_DIM * 64) + doff;
        const u16* vb = Vb + (size_t)s * (T_DIM * 64) + doff;
        #pragma unroll
        for (int t = 0; t < T_DIM; ++t) {
            ku[t] = *(const u32*)(kb + t * 64);
            vu[t] = *(const u32*)(vb + t * 64);
        }
        bool val = i < e1;
        const float* gp = gate + (size_t)s * T_DIM;
        float2 g01 = *(const float2*)(gp);
        float2 g23 = *(const float2*)(gp + 2);
        float2 g45 = *(const float2*)(gp + 4);
        gg[0] = val ? g01.x : NEGBIG; gg[1] = val ? g01.y : NEGBIG;
        gg[2] = val ? g23.x : NEGBIG; gg[3] = val ? g23.y : NEGBIG;
        gg[4] = val ? g45.x : NEGBIG; gg[5] = val ? g45.y : NEGBIG;
    }

    for (int p = 0; p < npairs; ++p) {
        // ---- prefetch next pair (clamped; overlaps the compute below) ----
        u32 ku2[T_DIM], vu2[T_DIM];
        float gg2[T_DIM];
        {
            int i = e0 + (p + 1) * 2 + half;
            int s = edge_src[min(i, e1 - 1)];
            const u16* kb = Kb + (size_t)s * (T_DIM * 64) + doff;
            const u16* vb = Vb + (size_t)s * (T_DIM * 64) + doff;
            #pragma unroll
            for (int t = 0; t < T_DIM; ++t) {
                ku2[t] = *(const u32*)(kb + t * 64);
                vu2[t] = *(const u32*)(vb + t * 64);
            }
            bool val = i < e1;
            const float* gp = gate + (size_t)s * T_DIM;
            float2 g01 = *(const float2*)(gp);
            float2 g23 = *(const float2*)(gp + 2);
            float2 g45 = *(const float2*)(gp + 4);
            gg2[0] = val ? g01.x : NEGBIG; gg2[1] = val ? g01.y : NEGBIG;
            gg2[2] = val ? g23.x : NEGBIG; gg2[3] = val ? g23.y : NEGBIG;
            gg2[4] = val ? g45.x : NEGBIG; gg2[5] = val ? g45.y : NEGBIG;
        }
        // ---- compute current pair ----
        float k0[T_DIM], k1[T_DIM], v0[T_DIM], v1[T_DIM];
        #pragma unroll
        for (int t = 0; t < T_DIM; ++t) {
            k0[t] = __int_as_float((int)(ku[t] << 16));
            k1[t] = __int_as_float((int)(ku[t] & 0xffff0000u));
            v0[t] = __int_as_float((int)(vu[t] << 16));
            v1[t] = __int_as_float((int)(vu[t] & 0xffff0000u));
        }
        #pragma unroll
        for (int t = 0; t < T_DIM; ++t) {
            #pragma unroll
            for (int dt = 0; dt <= t; ++dt) {
                int tp = t - dt;
                float d = red8(fmaf(q1[t], k1[tp], q0[t] * k0[tp]));
                float wt = fast_exp2(d + cc[t * (t + 1) / 2 + dt] + gg[tp]);
                den[t] += wt;
                nu0[t] = fmaf(wt, v0[tp], nu0[t]);
                nu1[t] = fmaf(wt, v1[tp], nu1[t]);
            }
        }
        #pragma unroll
        for (int t = 0; t < T_DIM; ++t) { ku[t] = ku2[t]; vu[t] = vu2[t]; gg[t] = gg2[t]; }
    }

    // combine the two edge-halves (once per node), then store
    #pragma unroll
    for (int t = 0; t < T_DIM; ++t) {
        den[t] += __shfl_xor(den[t], 32);
        nu0[t] += __shfl_xor(nu0[t], 32);
        nu1[t] += __shfl_xor(nu1[t], 32);
    }
    if (half == 0) {
        #pragma unroll
        for (int t = 0; t < T_DIM; ++t) {
            float r = 1.0f / fmaxf(den[t], 1e-12f);
            *(float2*)(out + ((size_t)t * N_NODES + n) * 64 + doff) =
                make_float2(nu0[t] * r, nu1[t] * r);
        }
    }
}

extern "C" void kernel_launch(void* const* d_in, const int* in_sizes, int n_in,
                              void* d_out, int out_size, void* d_ws, size_t ws_size,
                              hipStream_t stream) {
    const float* H  = (const float*)d_in[0];
    const float* S  = (const float*)d_in[1];
    const float* Wq = (const float*)d_in[2];
    const float* Wk = (const float*)d_in[3];
    const float* Wv = (const float*)d_in[4];
    const int* edge = (const int*)d_in[5];
    int E = in_sizes[5] / 2;
    const int* esrc = edge;
    const int* edst = edge + E;
    float* out = (float*)d_out;

    char* ws = (char*)d_ws;
    size_t off = 0;
    auto alloc = [&](size_t b) { char* p = ws + off; off += (b + 255) & ~(size_t)255; return (void*)p; };
    u16*   Kb       = (u16*)  alloc((size_t)TOTAL_ROWS * 64 * 2);   // 7.68 MB
    u16*   Vb       = (u16*)  alloc((size_t)TOTAL_ROWS * 64 * 2);   // 7.68 MB
    float* gate     = (float*)alloc((size_t)TOTAL_ROWS * 4);        // 240 KB
    float* kpe      = (float*)alloc(9 * 64 * 4);
    float* bias     = (float*)alloc(9 * 4);
    int*   counts   = (int*)  alloc((size_t)N_NODES * 4);
    int*   cursor   = (int*)  alloc((size_t)N_NODES * 4);
    int*   row_ptr  = (int*)  alloc((size_t)(N_NODES + 1) * 4);
    int*   edge_src = (int*)  alloc((size_t)E * 4);

    hipMemsetAsync(counts, 0, (size_t)N_NODES * sizeof(int), stream);
    prep_kernel<<<(TOTAL_ROWS + 255) / 256, 256, 0, stream>>>(S, Wk, edst, gate, kpe, bias, counts, E);
    scan_kernel<<<1, SCAN_THREADS, 0, stream>>>(counts, row_ptr, cursor);
    scatter_kernel<<<(E + 255) / 256, 256, 0, stream>>>(esrc, edst, cursor, edge_src, E);
    proj_kernel<<<TOTAL_ROWS / 32, 256, 0, stream>>>(H, Wq, Wk, Wv, out, Kb, Vb);
    agg_kernel<<<(N_NODES + 3) / 4, 256, 0, stream>>>(out, Kb, Vb, gate, kpe, bias, row_ptr, edge_src, out);
}

// Round 3
// 76.309 us; speedup vs baseline: 1.8120x; 1.2834x over previous
//
#include <hip/hip_runtime.h>
#include <hip/hip_bf16.h>

#define T_DIM 6
#define N_NODES 10000
#define TOTAL_ROWS (T_DIM * N_NODES)   // 60000
#define LOG2E 1.44269504088896340736f
#define QPRE (0.25f * LOG2E)           // dh^-0.5 * log2(e): softmax done in exp2 domain
#define EPS_GATE 1e-6f
#define NEGBIG (-1e30f)

typedef unsigned int u32;
typedef unsigned short u16;
typedef __attribute__((ext_vector_type(8))) short bf16x8;
typedef __attribute__((ext_vector_type(4))) float f32x4;

#define MFMA16(a, b, c) __builtin_amdgcn_mfma_f32_16x16x32_bf16(a, b, c, 0, 0, 0)

__device__ __forceinline__ float fast_exp2(float x) {
#if __has_builtin(__builtin_amdgcn_exp2f)
    return __builtin_amdgcn_exp2f(x);
#else
    return exp2f(x);
#endif
}

// DPP butterfly add within 8-lane groups.
template <int CTRL>
__device__ __forceinline__ float dpp_add(float x) {
    int v = __builtin_amdgcn_update_dpp(0, __float_as_int(x), CTRL, 0xf, 0xf, true);
    return x + __int_as_float(v);
}
__device__ __forceinline__ float red8(float x) {
    x = dpp_add<0xB1>(x);   // quad_perm {1,0,3,2}  : lane ^ 1
    x = dpp_add<0x4E>(x);   // quad_perm {2,3,0,1}  : lane ^ 2
    x = dpp_add<0x141>(x);  // row_half_mirror      : l -> 7-l within 8
    return x;
}

__device__ __forceinline__ float bf2f(u16 u) {
    union { unsigned int i; float f; } c;
    c.i = ((unsigned int)u) << 16;
    return c.f;
}

__device__ __forceinline__ u16 f2bf(float f) {
    union { float f; unsigned int i; } c; c.f = f;
    unsigned int i = c.i;
    unsigned int lsb = (i >> 16) & 1u;
    i += 0x7FFFu + lsb;          // round-to-nearest-even (finite data only)
    return (u16)(i >> 16);
}

// ---------------- prep: gate table (log2 domain), K_pe table, degree counts ----------------
__global__ void prep_kernel(const float* __restrict__ S,
                            const float* __restrict__ Wk,     // (64,72)
                            const int* __restrict__ edge_dst, // E
                            float* __restrict__ gate,         // [N][T], log2(S+eps)
                            float* __restrict__ kpe,          // [9][64]
                            float* __restrict__ bias,         // [9], -log2(1+dt)
                            int* __restrict__ counts, int E) {
    int idx = blockIdx.x * blockDim.x + threadIdx.x;
    if (idx < TOTAL_ROWS) {
        int t = idx / N_NODES, n = idx - t * N_NODES;
        gate[n * T_DIM + t] = log2f(S[idx] + EPS_GATE);
    }
    if (idx < E) atomicAdd(&counts[edge_dst[idx]], 1);
    if (blockIdx.x == 0 && threadIdx.x < 64) {
        int c = threadIdx.x;
        for (int dt = 0; dt < 9; ++dt) {
            float fdt = (float)dt;
            float pe[8];
            pe[0] = expf(-fdt * 0.25f);    // tau=4
            pe[1] = expf(-fdt * 0.0625f);  // tau=16
            pe[2] = sinf(fdt * 1.0f);
            pe[3] = sinf(fdt * 0.5f);
            pe[4] = sinf(fdt * 0.25f);
            pe[5] = cosf(fdt * 1.0f);
            pe[6] = cosf(fdt * 0.5f);
            pe[7] = cosf(fdt * 0.25f);
            float acc = 0.f;
            #pragma unroll
            for (int j = 0; j < 8; ++j) acc += pe[j] * Wk[c * 72 + 64 + j];
            kpe[dt * 64 + c] = acc;
            if (c == 0) bias[dt] = -log2f(1.0f + fdt);
        }
    }
}

// ---------------- single-block exclusive scan -> CSR row_ptr ----------------
#define SCAN_THREADS 1024
#define SCAN_CHUNK 10            // 1024*10 >= 10000
__global__ void scan_kernel(const int* __restrict__ counts,
                            int* __restrict__ row_ptr,   // N+1
                            int* __restrict__ cursor) {
    __shared__ int sums[SCAN_THREADS];
    int tid = threadIdx.x;
    int start = tid * SCAN_CHUNK;
    int local[SCAN_CHUNK];
    int s = 0;
    #pragma unroll
    for (int j = 0; j < SCAN_CHUNK; ++j) {
        int idx = start + j;
        int v = (idx < N_NODES) ? counts[idx] : 0;
        local[j] = s; s += v;
    }
    sums[tid] = s;
    __syncthreads();
    for (int off = 1; off < SCAN_THREADS; off <<= 1) {
        int v = sums[tid];
        int o = (tid >= off) ? sums[tid - off] : 0;
        __syncthreads();
        sums[tid] = v + o;
        __syncthreads();
    }
    int base = (tid > 0) ? sums[tid - 1] : 0;
    #pragma unroll
    for (int j = 0; j < SCAN_CHUNK; ++j) {
        int idx = start + j;
        if (idx < N_NODES) {
            int val = base + local[j];
            row_ptr[idx] = val;
            cursor[idx] = val;
        }
    }
    if (tid == SCAN_THREADS - 1) row_ptr[N_NODES] = sums[SCAN_THREADS - 1];
}

// ---------------- scatter edges into CSR buckets ----------------
__global__ void scatter_kernel(const int* __restrict__ esrc, const int* __restrict__ edst,
                               int* __restrict__ cursor, int* __restrict__ edge_src, int E) {
    int e = blockIdx.x * blockDim.x + threadIdx.x;
    if (e < E) {
        int pos = atomicAdd(&cursor[edst[e]], 1);
        edge_src[pos] = esrc[e];
    }
}

// ---------------- fused QKV projection via split-bf16 MFMA ----------------
// C[row, col] = sum_k H[row,k] * W[col,k], cols 0-63 Q, 64-127 K, 128-191 V.
// f32 accuracy recovered via h = hi + lo (bf16 pair): h*w ~= hi*whi + hi*wlo + lo*whi.
__global__ __launch_bounds__(256) void proj_kernel(
    const float* __restrict__ H,
    const float* __restrict__ Wq, const float* __restrict__ Wk,
    const float* __restrict__ Wv,
    float* __restrict__ Qs, u16* __restrict__ Kb, u16* __restrict__ Vb) {
    __shared__ short whi[192][72];   // stride 72 shorts = 144B -> 2-way banks (free)
    __shared__ short wlo[192][72];
    int tid = threadIdx.x;
    for (int i = tid; i < 192 * 64; i += 256) {
        int col = i >> 6, k = i & 63;
        float w;
        if (col < 64)       w = Wq[col * 64 + k];
        else if (col < 128) w = Wk[(col - 64) * 72 + k];   // first 64 input dims of W_k
        else                w = Wv[(col - 128) * 64 + k];
        u16 hb = f2bf(w);
        u16 lb = f2bf(w - bf2f(hb));
        whi[col][k] = (short)hb;
        wlo[col][k] = (short)lb;
    }
    __syncthreads();

    int lane = tid & 63, wid = tid >> 6;
    int r0 = (blockIdx.x * 4 + wid) * 32;          // 32 rows per wave (60000 = 32*1875)
    if (r0 >= TOTAL_ROWS) return;

    int mrow = lane & 15;
    int kgrp = lane >> 4;                          // 0..3

    // A fragments: [mtile][kstep], hi+lo split
    bf16x8 ahi[2][2], alo[2][2];
    #pragma unroll
    for (int mt = 0; mt < 2; ++mt) {
        #pragma unroll
        for (int ks = 0; ks < 2; ++ks) {
            const float* hp = H + (size_t)(r0 + mt * 16 + mrow) * 64 + ks * 32 + kgrp * 8;
            float4 hA = *(const float4*)hp;
            float4 hB = *(const float4*)(hp + 4);
            float tmp[8] = {hA.x, hA.y, hA.z, hA.w, hB.x, hB.y, hB.z, hB.w};
            #pragma unroll
            for (int b = 0; b < 8; ++b) {
                u16 hb = f2bf(tmp[b]);
                u16 lb = f2bf(tmp[b] - bf2f(hb));
                ahi[mt][ks][b] = (short)hb;
                alo[mt][ks][b] = (short)lb;
            }
        }
    }

    #pragma unroll
    for (int nt = 0; nt < 12; ++nt) {
        f32x4 acc0 = {0.f, 0.f, 0.f, 0.f};
        f32x4 acc1 = {0.f, 0.f, 0.f, 0.f};
        #pragma unroll
        for (int ks = 0; ks < 2; ++ks) {
            bf16x8 bh = *(const bf16x8*)&whi[nt * 16 + mrow][ks * 32 + kgrp * 8];
            bf16x8 bl = *(const bf16x8*)&wlo[nt * 16 + mrow][ks * 32 + kgrp * 8];
            acc0 = MFMA16(ahi[0][ks], bh, acc0);
            acc0 = MFMA16(ahi[0][ks], bl, acc0);
            acc0 = MFMA16(alo[0][ks], bh, acc0);
            acc1 = MFMA16(ahi[1][ks], bh, acc1);
            acc1 = MFMA16(ahi[1][ks], bl, acc1);
            acc1 = MFMA16(alo[1][ks], bh, acc1);
        }
        // epilogue: C col = lane&15, row = (lane>>4)*4 + j   [m89-verified]
        #pragma unroll
        for (int mt = 0; mt < 2; ++mt) {
            f32x4 acc = mt ? acc1 : acc0;
            int mbase = r0 + mt * 16 + kgrp * 4;
            #pragma unroll
            for (int j = 0; j < 4; ++j) {
                int gr = mbase + j;
                float v = acc[j];
                if (nt < 4) {
                    Qs[(size_t)gr * 64 + nt * 16 + mrow] = v * QPRE;
                } else if (nt < 8) {
                    int t = gr / N_NODES, n = gr - t * N_NODES;
                    Kb[((size_t)n * T_DIM + t) * 64 + (nt - 4) * 16 + mrow] = f2bf(v);
                } else {
                    int t = gr / N_NODES, n = gr - t * N_NODES;
                    Vb[((size_t)n * T_DIM + t) * 64 + (nt - 8) * 16 + mrow] = f2bf(v);
                }
            }
        }
    }
}

// ---------------- aggregation: one wave per node, 2 edges per iteration ----------------
// lanes: [half(2 edges)][head(4)][pair(8)], each lane owns 2 consecutive dims.
__global__ __launch_bounds__(256) void agg_kernel(
    const float* __restrict__ Qs,     // [t][n][64], prescaled by QPRE (aliases out)
    const u16* __restrict__ Kb,       // [n][t][64] bf16
    const u16* __restrict__ Vb,
    const float* __restrict__ gate,   // [n][t]  log2(S+eps)
    const float* __restrict__ kpe,    // [9][64]
    const float* __restrict__ bias,   // [9]  -log2(1+dt)
    const int* __restrict__ row_ptr,
    const int* __restrict__ edge_src,
    float* __restrict__ out) {
    int lane = threadIdx.x & 63, w = threadIdx.x >> 6;
    int n = blockIdx.x * 4 + w;
    int half = lane >> 5;
    int l32 = lane & 31;
    int doff = ((l32 >> 3) << 4) + ((l32 & 7) << 1);   // h*16 + 2*p

    float q0[T_DIM], q1[T_DIM];
    #pragma unroll
    for (int t = 0; t < T_DIM; ++t) {
        float2 qq = *(const float2*)(Qs + ((size_t)t * N_NODES + n) * 64 + doff);
        q0[t] = qq.x; q1[t] = qq.y;
    }

    int e0 = row_ptr[n], e1 = row_ptr[n + 1];
    if (e0 >= e1) {                                    // zero-degree: output 0 (matches ref clip)
        if (half == 0) {
            #pragma unroll
            for (int t = 0; t < T_DIM; ++t)
                *(float2*)(out + ((size_t)t * N_NODES + n) * 64 + doff) = make_float2(0.f, 0.f);
        }
        return;
    }

    // cc[tri(t,dt)] = dot(q[t], K_pe[dt]) + bias[dt]   (log2 domain; uniform per head group)
    float cc[21];
    #pragma unroll
    for (int dt = 0; dt < T_DIM; ++dt) {
        float2 kp = *(const float2*)(kpe + dt * 64 + doff);
        float b = bias[dt];
        #pragma unroll
        for (int t = dt; t < T_DIM; ++t)
            cc[t * (t + 1) / 2 + dt] = red8(fmaf(q1[t], kp.y, q0[t] * kp.x)) + b;
    }

    float den[T_DIM] = {0,0,0,0,0,0};
    float nu0[T_DIM] = {0,0,0,0,0,0};
    float nu1[T_DIM] = {0,0,0,0,0,0};

    int npairs = (e1 - e0 + 1) >> 1;
    u32 ku[T_DIM], vu[T_DIM];
    float gg[T_DIM];

    // prologue: load pair 0 (this half's edge; odd tail padded via g = -1e30 -> weight 0)
    {
        int i = e0 + half;
        int s = edge_src[min(i, e1 - 1)];
        const u16* kb = Kb + (size_t)s * (T_DIM * 64) + doff;
        const u16* vb = Vb + (size_t)s * (T_DIM * 64) + doff;
        #pragma unroll
        for (int t = 0; t < T_DIM; ++t) {
            ku[t] = *(const u32*)(kb + t * 64);
            vu[t] = *(const u32*)(vb + t * 64);
        }
        bool val = i < e1;
        const float* gp = gate + (size_t)s * T_DIM;
        float2 g01 = *(const float2*)(gp);
        float2 g23 = *(const float2*)(gp + 2);
        float2 g45 = *(const float2*)(gp + 4);
        gg[0] = val ? g01.x : NEGBIG; gg[1] = val ? g01.y : NEGBIG;
        gg[2] = val ? g23.x : NEGBIG; gg[3] = val ? g23.y : NEGBIG;
        gg[4] = val ? g45.x : NEGBIG; gg[5] = val ? g45.y : NEGBIG;
    }

    for (int p = 0; p < npairs; ++p) {
        // ---- prefetch next pair (clamped; overlaps the compute below) ----
        u32 ku2[T_DIM], vu2[T_DIM];
        float gg2[T_DIM];
        {
            int i = e0 + (p + 1) * 2 + half;
            int s = edge_src[min(i, e1 - 1)];
            const u16* kb = Kb + (size_t)s * (T_DIM * 64) + doff;
            const u16* vb = Vb + (size_t)s * (T_DIM * 64) + doff;
            #pragma unroll
            for (int t = 0; t < T_DIM; ++t) {
                ku2[t] = *(const u32*)(kb + t * 64);
                vu2[t] = *(const u32*)(vb + t * 64);
            }
            bool val = i < e1;
            const float* gp = gate + (size_t)s * T_DIM;
            float2 g01 = *(const float2*)(gp);
            float2 g23 = *(const float2*)(gp + 2);
            float2 g45 = *(const float2*)(gp + 4);
            gg2[0] = val ? g01.x : NEGBIG; gg2[1] = val ? g01.y : NEGBIG;
            gg2[2] = val ? g23.x : NEGBIG; gg2[3] = val ? g23.y : NEGBIG;
            gg2[4] = val ? g45.x : NEGBIG; gg2[5] = val ? g45.y : NEGBIG;
        }
        // ---- compute current pair ----
        float k0[T_DIM], k1[T_DIM], v0[T_DIM], v1[T_DIM];
        #pragma unroll
        for (int t = 0; t < T_DIM; ++t) {
            k0[t] = __int_as_float((int)(ku[t] << 16));
            k1[t] = __int_as_float((int)(ku[t] & 0xffff0000u));
            v0[t] = __int_as_float((int)(vu[t] << 16));
            v1[t] = __int_as_float((int)(vu[t] & 0xffff0000u));
        }
        #pragma unroll
        for (int t = 0; t < T_DIM; ++t) {
            #pragma unroll
            for (int dt = 0; dt <= t; ++dt) {
                int tp = t - dt;
                float d = red8(fmaf(q1[t], k1[tp], q0[t] * k0[tp]));
                float wt = fast_exp2(d + cc[t * (t + 1) / 2 + dt] + gg[tp]);
                den[t] += wt;
                nu0[t] = fmaf(wt, v0[tp], nu0[t]);
                nu1[t] = fmaf(wt, v1[tp], nu1[t]);
            }
        }
        #pragma unroll
        for (int t = 0; t < T_DIM; ++t) { ku[t] = ku2[t]; vu[t] = vu2[t]; gg[t] = gg2[t]; }
    }

    // combine the two edge-halves (once per node), then store
    #pragma unroll
    for (int t = 0; t < T_DIM; ++t) {
        den[t] += __shfl_xor(den[t], 32);
        nu0[t] += __shfl_xor(nu0[t], 32);
        nu1[t] += __shfl_xor(nu1[t], 32);
    }
    if (half == 0) {
        #pragma unroll
        for (int t = 0; t < T_DIM; ++t) {
            float r = 1.0f / fmaxf(den[t], 1e-12f);
            *(float2*)(out + ((size_t)t * N_NODES + n) * 64 + doff) =
                make_float2(nu0[t] * r, nu1[t] * r);
        }
    }
}

extern "C" void kernel_launch(void* const* d_in, const int* in_sizes, int n_in,
                              void* d_out, int out_size, void* d_ws, size_t ws_size,
                              hipStream_t stream) {
    const float* H  = (const float*)d_in[0];
    const float* S  = (const float*)d_in[1];
    const float* Wq = (const float*)d_in[2];
    const float* Wk = (const float*)d_in[3];
    const float* Wv = (const float*)d_in[4];
    const int* edge = (const int*)d_in[5];
    int E = in_sizes[5] / 2;
    const int* esrc = edge;
    const int* edst = edge + E;
    float* out = (float*)d_out;

    char* ws = (char*)d_ws;
    size_t off = 0;
    auto alloc = [&](size_t b) { char* p = ws + off; off += (b + 255) & ~(size_t)255; return (void*)p; };
    u16*   Kb       = (u16*)  alloc((size_t)TOTAL_ROWS * 64 * 2);   // 7.68 MB
    u16*   Vb       = (u16*)  alloc((size_t)TOTAL_ROWS * 64 * 2);   // 7.68 MB
    float* gate     = (float*)alloc((size_t)TOTAL_ROWS * 4);        // 240 KB
    float* kpe      = (float*)alloc(9 * 64 * 4);
    float* bias     = (float*)alloc(9 * 4);
    int*   counts   = (int*)  alloc((size_t)N_NODES * 4);
    int*   cursor   = (int*)  alloc((size_t)N_NODES * 4);
    int*   row_ptr  = (int*)  alloc((size_t)(N_NODES + 1) * 4);
    int*   edge_src = (int*)  alloc((size_t)E * 4);

    hipMemsetAsync(counts, 0, (size_t)N_NODES * sizeof(int), stream);
    prep_kernel<<<(TOTAL_ROWS + 255) / 256, 256, 0, stream>>>(S, Wk, edst, gate, kpe, bias, counts, E);
    scan_kernel<<<1, SCAN_THREADS, 0, stream>>>(counts, row_ptr, cursor);
    scatter_kernel<<<(E + 255) / 256, 256, 0, stream>>>(esrc, edst, cursor, edge_src, E);
    int proj_blocks = (TOTAL_ROWS / 32 + 3) / 4;   // 1875 waves / 4 per block
    proj_kernel<<<proj_blocks, 256, 0, stream>>>(H, Wq, Wk, Wv, out, Kb, Vb);
    agg_kernel<<<(N_NODES + 3) / 4, 256, 0, stream>>>(out, Kb, Vb, gate, kpe, bias, row_ptr, edge_src, out);
}